// Round 8
// baseline (227.569 us; speedup 1.0000x reference)
//
#include <hip/hip_runtime.h>

// z_e: [B=64, D=64, H=64, W=64] fp32 ; embeddings: [K=512, D=64] fp32
// out: z_q_st [64,64,64,64] fp32 ++ loss (1 fp32)
constexpr int Dc  = 64;
constexpr int Kc  = 512;
constexpr int HWc = 4096;
constexpr int Nc  = 64 * HWc;                    // 262144 points
constexpr float INV_ELEMS = 1.0f / 16777216.0f;
constexpr float FLAG_HALF = 0.00625f;            // W/2, W = 0.0125 dist-window

constexpr int LDS_EPOS = 131072;                 // byte offset of eposneg copy
constexpr int LDS_RED  = 131072 + 2048;          // byte offset of reduce array
constexpr int LDS_TOT  = LDS_RED + 64;

typedef __attribute__((ext_vector_type(8))) short bf16x8;
typedef __attribute__((ext_vector_type(4))) float f32x4;

static __device__ __forceinline__ short f2bf(float x) {   // RNE fp32->bf16
    unsigned u = __builtin_bit_cast(unsigned, x);
    unsigned r = (u + 0x7FFFu + ((u >> 16) & 1u)) >> 16;
    return (short)r;
}
static __device__ __forceinline__ float bf2f(short h) {
    unsigned u = ((unsigned)(unsigned short)h) << 16;
    return __builtin_bit_cast(float, u);
}

// ---- K1: prep — pack E fragment stream + eposneg ---------------------------
// q<8192: 16B chunk q: kt=q>>8, lo=(q>>7)&1, c=(q>>6)&1, lane=q&63;
// content = {hi|lo} bf16 of emb[kt*16+(lane&15)][c*32+(lane>>4)*8 .. +8).
// q in [8192,8704): eposneg[k] = -0.5*||e_k||^2, k = q-8192.
__global__ __launch_bounds__(256) void vq_prep(const float* __restrict__ emb,
                                               short* __restrict__ EF,
                                               float* __restrict__ eposneg) {
    int q = blockIdx.x * 256 + threadIdx.x;
    if (q < 8192) {
        int kt = q >> 8, lo = (q >> 7) & 1, c = (q >> 6) & 1, lane = q & 63;
        int code = kt * 16 + (lane & 15);
        int d0   = c * 32 + (lane >> 4) * 8;
        const float* e = emb + (size_t)code * Dc + d0;
        bf16x8 v;
#pragma unroll
        for (int j = 0; j < 8; ++j) {
            float x = e[j];
            short h = f2bf(x);
            v[j] = lo ? f2bf(x - bf2f(h)) : h;
        }
        *reinterpret_cast<bf16x8*>(EF + (size_t)q * 8) = v;
    } else if (q < 8192 + Kc) {
        int k = q - 8192;
        const float* e = emb + (size_t)k * Dc;
        float s0 = 0.f, s1 = 0.f, s2 = 0.f, s3 = 0.f;
#pragma unroll
        for (int d = 0; d < 16; ++d) {
            float v0 = e[d], v1 = e[16 + d], v2 = e[32 + d], v3 = e[48 + d];
            s0 = fmaf(v0, v0, s0); s1 = fmaf(v1, v1, s1);
            s2 = fmaf(v2, v2, s2); s3 = fmaf(v3, v3, s3);
        }
        eposneg[k] = -0.5f * ((s0 + s1) + (s2 + s3));
    }
}

// ---- K2: main --------------------------------------------------------------
// 256 blocks (1/CU) x 1024 thr (16 waves, 4/SIMD). Wave owns 64 points as two
// groups of 32 (2 MFMA point-tiles each). Per kt: split 6-MFMA chain into two
// 3-deep halves (c = pA + pB); argmax runs ONE kt behind (even/odd buffers) so
// its VALU overlaps in-flight MFMAs. eposneg read from LDS.
__global__ __launch_bounds__(1024)
void vq_main(const float* __restrict__ z_e, const float* __restrict__ emb,
             const short* __restrict__ EF, const float* __restrict__ eposneg,
             float* __restrict__ out, float* __restrict__ acc,
             unsigned int* __restrict__ flags) {
    extern __shared__ __align__(16) char smem[];
    const int tid = threadIdx.x;

    // stage 128 KB E fragment stream + 2 KB eposneg
    {
        const bf16x8* src = reinterpret_cast<const bf16x8*>(EF);
        bf16x8*       dst = reinterpret_cast<bf16x8*>(smem);
#pragma unroll
        for (int i = 0; i < 8; ++i) dst[tid + i * 1024] = src[tid + i * 1024];
        if (tid < Kc) ((float*)(smem + LDS_EPOS))[tid] = eposneg[tid];
    }
    __syncthreads();
    const float* eposL = (const float*)(smem + LDS_EPOS);

    const int wave = tid >> 6, lane = tid & 63;
    const int p16 = lane & 15, g = lane >> 4;
    const int g4 = g * 4, lane16 = lane * 16;
    const int b   = blockIdx.x >> 2;                     // 1024 points/block
    const int hwb = (blockIdx.x & 3) * 1024 + wave * 64;
    const int pbase0 = blockIdx.x * 1024 + wave * 64;
    const f32x4 zero4 = {0.f, 0.f, 0.f, 0.f};

    float lsum = 0.f;

#define COMPUTE(C0, C1, KT)                                                      \
    {                                                                            \
        const char* eb_ = smem + (KT) * 4096 + lane16;                           \
        bf16x8 eh0_ = *reinterpret_cast<const bf16x8*>(eb_);                     \
        bf16x8 eh1_ = *reinterpret_cast<const bf16x8*>(eb_ + 1024);              \
        bf16x8 el0_ = *reinterpret_cast<const bf16x8*>(eb_ + 2048);              \
        bf16x8 el1_ = *reinterpret_cast<const bf16x8*>(eb_ + 3072);              \
        f32x4 en_ = *reinterpret_cast<const f32x4*>(eposL + (KT) * 16 + g4);     \
        f32x4 p_, q_;                                                            \
        p_ = __builtin_amdgcn_mfma_f32_16x16x32_bf16(eh0_, zh[0][0], en_, 0,0,0);\
        p_ = __builtin_amdgcn_mfma_f32_16x16x32_bf16(eh1_, zh[0][1], p_, 0,0,0); \
        p_ = __builtin_amdgcn_mfma_f32_16x16x32_bf16(eh0_, zl[0][0], p_, 0,0,0); \
        q_ = __builtin_amdgcn_mfma_f32_16x16x32_bf16(eh1_, zl[0][1], zero4,0,0,0);\
        q_ = __builtin_amdgcn_mfma_f32_16x16x32_bf16(el0_, zh[0][0], q_, 0,0,0); \
        q_ = __builtin_amdgcn_mfma_f32_16x16x32_bf16(el1_, zh[0][1], q_, 0,0,0); \
        C0 = p_ + q_;                                                            \
        p_ = __builtin_amdgcn_mfma_f32_16x16x32_bf16(eh0_, zh[1][0], en_, 0,0,0);\
        p_ = __builtin_amdgcn_mfma_f32_16x16x32_bf16(eh1_, zh[1][1], p_, 0,0,0); \
        p_ = __builtin_amdgcn_mfma_f32_16x16x32_bf16(eh0_, zl[1][0], p_, 0,0,0); \
        q_ = __builtin_amdgcn_mfma_f32_16x16x32_bf16(eh1_, zl[1][1], zero4,0,0,0);\
        q_ = __builtin_amdgcn_mfma_f32_16x16x32_bf16(el0_, zh[1][0], q_, 0,0,0); \
        q_ = __builtin_amdgcn_mfma_f32_16x16x32_bf16(el1_, zh[1][1], q_, 0,0,0); \
        C1 = p_ + q_;                                                            \
    }

#define ARGMAX(C0, C1, KT)                                  \
    {                                                       \
        _Pragma("unroll")                                   \
        for (int r_ = 0; r_ < 4; ++r_) {                    \
            float s0_ = (C0)[r_], s1_ = (C1)[r_];           \
            int code_ = (KT) * 16 + g4 + r_;                \
            bool gt0_ = s0_ > a1[0];                        \
            a2[0] = fmaxf(gt0_ ? a1[0] : s0_, a2[0]);       \
            i1[0] = gt0_ ? code_ : i1[0];                   \
            a1[0] = gt0_ ? s0_ : a1[0];                     \
            bool gt1_ = s1_ > a1[1];                        \
            a2[1] = fmaxf(gt1_ ? a1[1] : s1_, a2[1]);       \
            i1[1] = gt1_ ? code_ : i1[1];                   \
            a1[1] = gt1_ ? s1_ : a1[1];                     \
        }                                                   \
    }

#pragma unroll 1
    for (int grp = 0; grp < 2; ++grp) {
        const int hw0 = hwb + grp * 32;
        const float* zbase = z_e + (size_t)b * (Dc * HWc) + hw0;

        // Z fragments: element j -> Z[d = c*32+g*8+j][point = t*16+p16]
        bf16x8 zh[2][2], zl[2][2];
#pragma unroll
        for (int t = 0; t < 2; ++t)
#pragma unroll
            for (int c = 0; c < 2; ++c)
#pragma unroll
                for (int j = 0; j < 8; ++j) {
                    int d = c * 32 + g * 8 + j;
                    float zf = zbase[(size_t)d * HWc + t * 16 + p16];
                    short h = f2bf(zf);
                    zh[t][c][j] = h;
                    zl[t][c][j] = f2bf(zf - bf2f(h));
                }

        float a1[2] = {-3.4e38f, -3.4e38f}, a2[2] = {-3.4e38f, -3.4e38f};
        int   i1[2] = {0, 0};

        f32x4 cA0, cA1, cB0, cB1;
        COMPUTE(cA0, cA1, 0)
#pragma unroll 1
        for (int ktp = 0; ktp < 15; ++ktp) {
            const int kt = 1 + 2 * ktp;                  // 1,3,...,29
            COMPUTE(cB0, cB1, kt)
            ARGMAX(cA0, cA1, kt - 1)
            COMPUTE(cA0, cA1, kt + 1)
            ARGMAX(cB0, cB1, kt)
        }
        COMPUTE(cB0, cB1, 31)
        ARGMAX(cA0, cA1, 30)
        ARGMAX(cB0, cB1, 31)

        // merge (a1,i1,a2) across the 4 lane-groups (code subsets), per point
#pragma unroll
        for (int off = 16; off <= 32; off <<= 1)
#pragma unroll
            for (int t = 0; t < 2; ++t) {
                float oa1 = __shfl_xor(a1[t], off, 64);
                float oa2 = __shfl_xor(a2[t], off, 64);
                int   oi1 = __shfl_xor(i1[t], off, 64);
                float lo  = fminf(a1[t], oa1);
                a2[t] = fmaxf(fmaxf(a2[t], oa2), lo);
                bool take = (oa1 > a1[t]) || (oa1 == a1[t] && oi1 < i1[t]);
                a1[t] = take ? oa1 : a1[t];
                i1[t] = take ? oi1 : i1[t];
            }

        // flags: one 32-bit word per 32 points (this group's exact span)
        unsigned m[2];
#pragma unroll
        for (int t = 0; t < 2; ++t) {
            bool flg = (a1[t] - a2[t]) <= FLAG_HALF;     // near-tie in approx metric
            m[t] = (unsigned)(__ballot(g == 0 && flg) & 0xFFFFull);
        }
        if (lane == 0) flags[(pbase0 + grp * 32) / 32] = m[0] | (m[1] << 16);

        // epilogue: gather exact fp32 code rows, write z_q, loss from zh+zl
#pragma unroll
        for (int t = 0; t < 2; ++t) {
            const float* er = emb + (size_t)i1[t] * Dc;
            float* op = out + (size_t)b * (Dc * HWc) + hw0 + t * 16 + p16;
#pragma unroll
            for (int c = 0; c < 2; ++c)
#pragma unroll
                for (int j = 0; j < 8; ++j) {
                    int d = c * 32 + g * 8 + j;          // lane's own d-slots
                    float e = er[d];
                    op[(size_t)d * HWc] = e;
                    float zr = bf2f(zh[t][c][j]) + bf2f(zl[t][c][j]);
                    float f = e - zr;
                    lsum = fmaf(f, f, lsum);
                }
        }
    }
#undef COMPUTE
#undef ARGMAX

    // block-level loss reduction -> one atomic per block
    float v = lsum;
#pragma unroll
    for (int off = 32; off > 0; off >>= 1) v += __shfl_down(v, off);
    float* red = (float*)(smem + LDS_RED);
    if (lane == 0) red[wave] = v;
    __syncthreads();
    if (tid == 0) {
        float bs = 0.f;
#pragma unroll
        for (int w = 0; w < 16; ++w) bs += red[w];
        atomicAdd(acc, bs);
    }
}

// ---- K3: exact fp32 fixup for flagged points -------------------------------
__global__ __launch_bounds__(256) void vq_fixup(const float* __restrict__ z_e,
                                                const float* __restrict__ emb,
                                                const float* __restrict__ eposneg,
                                                const unsigned int* __restrict__ flags,
                                                float* __restrict__ out,
                                                float* __restrict__ acc) {
    const int lane = threadIdx.x & 63;
    const int wid  = (blockIdx.x * 256 + threadIdx.x) >> 6;
    const int nw   = (gridDim.x * 256) >> 6;
    for (int w = wid; w < Nc / 32; w += nw) {
        unsigned f = flags[w];
        while (f) {
            int bit = __ffs(f) - 1; f &= f - 1;
            int p = w * 32 + bit;
            int b = p >> 12, hw = p & 4095;
            const float* zp = z_e + (size_t)b * (Dc * HWc) + hw;
            float z[Dc];
#pragma unroll
            for (int d = 0; d < Dc; ++d) z[d] = zp[(size_t)d * HWc];  // broadcast
            float bd = 3.4e38f; int bi = 0;
#pragma unroll 1
            for (int r = 0; r < 8; ++r) {                // codes r*64 + lane
                int code = r * 64 + lane;
                const float* er = emb + (size_t)code * Dc;
                float s0 = 0.f, s1 = 0.f, s2 = 0.f, s3 = 0.f;
#pragma unroll
                for (int d = 0; d < 16; ++d) {           // R1-proven numerics
                    s0 = fmaf(er[d],      z[d],      s0);
                    s1 = fmaf(er[16 + d], z[16 + d], s1);
                    s2 = fmaf(er[32 + d], z[32 + d], s2);
                    s3 = fmaf(er[48 + d], z[48 + d], s3);
                }
                float dot  = (s0 + s1) + (s2 + s3);
                float dist = fmaf(-2.0f, dot, -2.0f * eposneg[code]); // +||e||^2
                if (dist < bd) { bd = dist; bi = code; } // within-lane ascending
            }
#pragma unroll
            for (int off = 32; off > 0; off >>= 1) {     // cross-lane argmin
                float od = __shfl_xor(bd, off, 64);
                int   oi = __shfl_xor(bi, off, 64);
                bool take = (od < bd) || (od == bd && oi < bi);
                bd = take ? od : bd;
                bi = take ? oi : bi;
            }
            // patch z_q column + loss delta (lane = d)
            float* op = out + (size_t)b * (Dc * HWc) + (size_t)lane * HWc + hw;
            float eo = *op;
            float en = emb[(size_t)bi * Dc + lane];
            float zf = zp[(size_t)lane * HWc];
            float dn = en - zf, dold = eo - zf;
            float delta = fmaf(dn, dn, -dold * dold);
            *op = en;
#pragma unroll
            for (int off = 32; off > 0; off >>= 1) delta += __shfl_down(delta, off);
            if (lane == 0) atomicAdd(acc, delta);
        }
    }
}

// ---- K4: finalize loss -----------------------------------------------------
__global__ void vq_finalize(const float* __restrict__ acc, float* __restrict__ out_loss) {
    out_loss[0] = 1.25f * (acc[0] * INV_ELEMS);
}

extern "C" void kernel_launch(void* const* d_in, const int* in_sizes, int n_in,
                              void* d_out, int out_size, void* d_ws, size_t ws_size,
                              hipStream_t stream) {
    const float* z_e = (const float*)d_in[0];
    const float* emb = (const float*)d_in[1];
    float* out = (float*)d_out;

    char* ws = (char*)d_ws;
    float*    acc     = (float*)(ws);                 // 4 B
    float*    eposneg = (float*)(ws + 256);           // 512 f32 = 2 KB
    unsigned* flags   = (unsigned*)(ws + 4096);       // N/32 u32 = 32 KB
    short*    EF      = (short*)(ws + 65536);         // 128 KB fragment stream

    hipFuncSetAttribute(reinterpret_cast<const void*>(vq_main),
                        hipFuncAttributeMaxDynamicSharedMemorySize, LDS_TOT);

    hipMemsetAsync(acc, 0, sizeof(float), stream);
    vq_prep<<<34, 256, 0, stream>>>(emb, EF, eposneg);
    vq_main<<<Nc / 1024, 1024, LDS_TOT, stream>>>(z_e, emb, EF, eposneg, out, acc, flags);
    vq_fixup<<<256, 256, 0, stream>>>(z_e, emb, eposneg, flags, out, acc);
    vq_finalize<<<1, 1, 0, stream>>>(acc, out + (size_t)Nc * Dc);
}